// Round 5
// baseline (798.065 us; speedup 1.0000x reference)
//
#include <hip/hip_runtime.h>
#include <stdint.h>

// Problem constants
// B=2, L=2048, D=512, H=8, DK=DV=64, TEMP=8, LN_EPS=1e-5

typedef float fx4 __attribute__((ext_vector_type(4)));
typedef short bfx8 __attribute__((ext_vector_type(8)));
typedef short sx4 __attribute__((ext_vector_type(4)));

#define MFMA16(a, b, c) __builtin_amdgcn_mfma_f32_16x16x32_bf16((a), (b), (c), 0, 0, 0)

__device__ __forceinline__ unsigned short f2bf(float f) {
  union { float f; uint32_t u; } v; v.f = f;
  uint32_t r = v.u + 0x7FFFu + ((v.u >> 16) & 1u);  // RNE
  return (unsigned short)(r >> 16);
}

__device__ __forceinline__ bfx8 ldbf8(const unsigned short* p) {
  return *reinterpret_cast<const bfx8*>(p);
}

__device__ __forceinline__ bfx8 cvt8(const float* p) {
  fx4 a = *reinterpret_cast<const fx4*>(p);
  fx4 b = *reinterpret_cast<const fx4*>(p + 4);
  bfx8 r;
  r[0] = (short)f2bf(a[0]); r[1] = (short)f2bf(a[1]);
  r[2] = (short)f2bf(a[2]); r[3] = (short)f2bf(a[3]);
  r[4] = (short)f2bf(b[0]); r[5] = (short)f2bf(b[1]);
  r[6] = (short)f2bf(b[2]); r[7] = (short)f2bf(b[3]);
  return r;
}

// ---------------- kernel 0: weight bf16 convert + mask bitpack (fused) ----------
__global__ __launch_bounds__(256) void k_prep(const float* __restrict__ s0,
                                              const float* __restrict__ s1,
                                              const float* __restrict__ s2,
                                              const float* __restrict__ s3,
                                              unsigned short* __restrict__ dst,
                                              const int* __restrict__ mask,
                                              unsigned long long* __restrict__ mbits) {
  int bid = blockIdx.x;
  if (bid < 1024) {
    int y = bid >> 8;
    const float* s = (y == 0) ? s0 : (y == 1) ? s1 : (y == 2) ? s2 : s3;
    int i = ((bid & 255) * 256 + threadIdx.x) * 4;
    fx4 v = *reinterpret_cast<const fx4*>(s + i);
    sx4 o;
    o[0] = (short)f2bf(v[0]); o[1] = (short)f2bf(v[1]);
    o[2] = (short)f2bf(v[2]); o[3] = (short)f2bf(v[3]);
    *reinterpret_cast<sx4*>(dst + y * 262144 + i) = o;
  } else {
    int i = (bid - 1024) * 256 + threadIdx.x;  // total 8388608
    unsigned long long b = __ballot(mask[i] != 0);
    if ((threadIdx.x & 63) == 0) mbits[i >> 6] = b;
  }
}

// ---------------- kernel 1: projection GEMMs, all 3 in one launch (blockIdx.z) --
// z=0: Qb [B,H,L,64] ; z=1: Kb same ; z=2: Vt [B,H,64,L] (transposed)
__global__ __launch_bounds__(256) void k_proj(const float* __restrict__ Xq,
                                              const float* __restrict__ Xk,
                                              const float* __restrict__ Xv,
                                              const unsigned short* __restrict__ Wb,
                                              const float* __restrict__ bq,
                                              const float* __restrict__ bk,
                                              const float* __restrict__ bv,
                                              unsigned short* __restrict__ Qb,
                                              unsigned short* __restrict__ Kb,
                                              unsigned short* __restrict__ Vt) {
  int z = blockIdx.z;
  const float* X = (z == 0) ? Xq : (z == 1) ? Xk : Xv;
  const unsigned short* W = Wb + (size_t)z * 262144;
  const float* bias = (z == 0) ? bq : (z == 1) ? bk : bv;
  unsigned short* dst = (z == 0) ? Qb : (z == 1) ? Kb : Vt;

  int wave = threadIdx.x >> 6, lane = threadIdx.x & 63;
  int quad = lane >> 4, tn = lane & 15;
  int m0 = blockIdx.x * 64 + wave * 16;   // 64 blocks.x -> 4096 rows
  int n0 = blockIdx.y * 64;               // 8 blocks.y  -> 512 cols
  fx4 acc[4];
  #pragma unroll
  for (int i = 0; i < 4; ++i) acc[i] = (fx4){0.f, 0.f, 0.f, 0.f};

  const float* xrow = X + (size_t)(m0 + tn) * 512;
  for (int k0 = 0; k0 < 512; k0 += 32) {
    bfx8 af = cvt8(xrow + k0 + quad * 8);
    #pragma unroll
    for (int nt = 0; nt < 4; ++nt) {
      const unsigned short* wp = W + (size_t)(n0 + nt * 16 + tn) * 512 + k0 + quad * 8;
      acc[nt] = MFMA16(af, ldbf8(wp), acc[nt]);
    }
  }

  #pragma unroll
  for (int nt = 0; nt < 4; ++nt) {
    int n = n0 + nt * 16 + tn;
    int h = n >> 6, dd = n & 63;
    float bvv = bias[n];
    if (z == 2) {
      int r0 = m0 + quad * 4;          // 4 consecutive rows, same batch
      int b = r0 >> 11, l = r0 & 2047;
      sx4 o;
      #pragma unroll
      for (int i = 0; i < 4; ++i) o[i] = (short)f2bf(acc[nt][i] + bvv);
      unsigned short* vp = dst + (size_t)((b * 8 + h) * 64 + dd) * 2048 + l;
      *reinterpret_cast<sx4*>(vp) = o;
    } else {
      #pragma unroll
      for (int i = 0; i < 4; ++i) {
        int r = m0 + quad * 4 + i;
        int b = r >> 11, l = r & 2047;
        dst[(size_t)((b * 8 + h) * 2048 + l) * 64 + dd] = f2bf(acc[nt][i] + bvv);
      }
    }
  }
}

// ---------------- kernel 2: single-pass attention, 8 q-rows, 8 waves -----------
// LDS 67.7 KB -> 2 blocks/CU: phase A (gate HBM read + QK MFMA) of one block
// overlaps phase B (attn HBM write) of the other. Rows duplicated 2x in MFMA
// tiles (cheap at ~3% MfmaUtil). Phase D split-K across all 8 waves.
#define SPITCH 2052
__global__ __launch_bounds__(512, 4) void k_attn(const unsigned short* __restrict__ Qb,
                                                 const unsigned short* __restrict__ Kb,
                                                 const unsigned short* __restrict__ Vt,
                                                 const float* __restrict__ gate,
                                                 const unsigned long long* __restrict__ mbits,
                                                 float* __restrict__ attn_out,
                                                 unsigned short* __restrict__ Ob) {
  __shared__ float S[8 * SPITCH];        // 65.7 KB score strip (front reused: bf16 P)
  __shared__ float Opart[4 * 8 * 16];    // 2 KB split-K partials

  int wave = threadIdx.x >> 6, lane = threadIdx.x & 63;
  int quad = lane >> 4, tn = lane & 15;

  int lin = blockIdx.x;            // 0..4095
  int xcd = lin & 7;
  int ix  = lin >> 3;              // 0..511
  int bh  = xcd * 2 + (ix >> 8);   // each XCD owns 2 (b,h): K/V stay L2-resident
  int qt  = ix & 255;
  int b = bh >> 3, h = bh & 7;
  int q0 = qt * 8;

  // ---- phase A: raw scores (QK^T)/8 -> LDS, gate prefetch interleaved --------
  const unsigned short* Qbase = Qb + ((size_t)bh * 2048 + q0) * 64;
  bfx8 aq0 = ldbf8(Qbase + (size_t)(tn & 7) * 64 + quad * 8);
  bfx8 aq1 = ldbf8(Qbase + (size_t)(tn & 7) * 64 + 32 + quad * 8);
  const unsigned short* Kbase = Kb + (size_t)bh * 2048 * 64;
  const float* grow0 = gate + ((size_t)bh * 2048 + q0 + wave) * 2048;

  fx4 gv[8];   // wave's q-row gate, 8 fx4/thread, fully unrolled -> VGPRs
  #pragma unroll
  for (int i2 = 0; i2 < 16; ++i2) {
    int kt = wave + i2 * 8;        // 16 key-tiles per wave, 8 waves cover 128
    int key0 = kt * 16;
    if (i2 < 8)
      gv[i2] = *reinterpret_cast<const fx4*>(grow0 + (size_t)(lane + i2 * 64) * 4);
    const unsigned short* kp = Kbase + (size_t)(key0 + tn) * 64 + quad * 8;
    bfx8 b0 = ldbf8(kp);
    bfx8 b1 = ldbf8(kp + 32);
    fx4 d = (fx4){0.f, 0.f, 0.f, 0.f};
    d = MFMA16(aq0, b0, d);
    d = MFMA16(aq1, b1, d);
    if (quad < 2) {                // rows 8..15 duplicate rows 0..7
      #pragma unroll
      for (int i = 0; i < 4; ++i)
        S[(quad * 4 + i) * SPITCH + key0 + tn] = d[i] * 0.125f;
    }
  }
  __syncthreads();

  // ---- phase B: wave w owns row w (full 64-lane reduce) ----------------------
  {
    float* srow = S + wave * SPITCH;
    const unsigned long long* mrow = mbits + (size_t)(b * 2048 + q0 + wave) * 32;
    unsigned long long mv[8];
    #pragma unroll
    for (int it = 0; it < 8; ++it) mv[it] = mrow[(lane + it * 64) >> 4];
    fx4 sv[8];
    float lmax = -3.0e38f;
    #pragma unroll
    for (int it = 0; it < 8; ++it) {
      int k4 = lane + it * 64;     // fx4 index 0..511
      fx4 s = *reinterpret_cast<fx4*>(srow + k4 * 4);
      fx4 g = gv[it];
      int sh = (k4 & 15) * 4;
      #pragma unroll
      for (int i = 0; i < 4; ++i) {
        float vv = s[i] * g[i];
        if ((mv[it] >> (sh + i)) & 1ull) vv = -3.0e38f;
        s[i] = vv;
        lmax = fmaxf(lmax, vv);
      }
      sv[it] = s;
    }
    #pragma unroll
    for (int off = 32; off; off >>= 1) lmax = fmaxf(lmax, __shfl_xor(lmax, off));
    float lsum = 0.f;
    #pragma unroll
    for (int it = 0; it < 8; ++it) {
      fx4 s = sv[it];
      #pragma unroll
      for (int i = 0; i < 4; ++i) {
        float p = __expf(s[i] - lmax);
        s[i] = p;
        lsum += p;
      }
      sv[it] = s;
    }
    #pragma unroll
    for (int off = 32; off; off >>= 1) lsum += __shfl_xor(lsum, off);
    float inv = 1.0f / lsum;
    float* orow = attn_out + ((size_t)bh * 2048 + q0 + wave) * 2048;
    unsigned short* pb = reinterpret_cast<unsigned short*>(srow);  // row front, bf16 P
    #pragma unroll
    for (int it = 0; it < 8; ++it) {
      int k4 = lane + it * 64;
      fx4 p = sv[it] * inv;
      *reinterpret_cast<fx4*>(orow + k4 * 4) = p;   // normalized attn (coalesced)
      sx4 pk;
      #pragma unroll
      for (int i = 0; i < 4; ++i) pk[i] = (short)f2bf(p[i]);
      *reinterpret_cast<sx4*>(pb + k4 * 4) = pk;    // normalized bf16 P for PV
    }
  }
  __syncthreads();

  // ---- phase D: split-K PV. wave w: dv [16(w&3), +16), keys half (w>>2) ------
  {
    int kw = wave & 3;
    int kb0 = (wave >> 2) * 32;    // key-tile offset 0 or 32 (x32 bf16 per tile)
    fx4 acc = (fx4){0.f, 0.f, 0.f, 0.f};
    const unsigned short* vbase = Vt + ((size_t)bh * 64 + kw * 16 + tn) * 2048;
    const unsigned short* prow = reinterpret_cast<const unsigned short*>(S + (tn & 7) * SPITCH);
    #pragma unroll 8
    for (int kt = 0; kt < 32; ++kt) {
      int k2 = kb0 + kt;
      bfx8 af = ldbf8(prow + k2 * 32 + quad * 8);
      bfx8 bv = ldbf8(vbase + k2 * 32 + quad * 8);
      acc = MFMA16(af, bv, acc);
    }
    if (wave >= 4 && quad < 2) {
      #pragma unroll
      for (int i = 0; i < 4; ++i)
        Opart[(wave - 4) * 128 + (quad * 4 + i) * 16 + tn] = acc[i];
    }
    __syncthreads();
    if (wave < 4 && quad < 2) {
      #pragma unroll
      for (int i = 0; i < 4; ++i) {
        float o = acc[i] + Opart[wave * 128 + (quad * 4 + i) * 16 + tn];
        int qg = q0 + quad * 4 + i;
        Ob[(size_t)(b * 2048 + qg) * 512 + h * 64 + kw * 16 + tn] = f2bf(o);
      }
    }
  }
}

// ---------------- kernel 3: FC + bias + residual + LayerNorm --------------------
// 8 rows/block, 512 blocks -> 2 blocks/CU (was 256 blocks = 1/CU, no overlap).
#define XPITCH 516
__global__ __launch_bounds__(256) void k_fc_ln(const unsigned short* __restrict__ Ob,
                                               const unsigned short* __restrict__ Wfcb,
                                               const float* __restrict__ bfc,
                                               const float* __restrict__ resid,
                                               const float* __restrict__ lng,
                                               const float* __restrict__ lnb,
                                               float* __restrict__ out) {
  __shared__ float xb[8 * XPITCH];
  int wave = threadIdx.x >> 6, lane = threadIdx.x & 63;
  int quad = lane >> 4, tn = lane & 15;
  int m0 = blockIdx.x * 8;   // 512 blocks -> 4096 rows

  fx4 acc[8];
  #pragma unroll
  for (int i = 0; i < 8; ++i) acc[i] = (fx4){0.f, 0.f, 0.f, 0.f};

  const unsigned short* arow = Ob + (size_t)(m0 + (tn & 7)) * 512;  // rows dup 2x
  for (int k0 = 0; k0 < 512; k0 += 32) {
    bfx8 af = ldbf8(arow + k0 + quad * 8);
    #pragma unroll
    for (int nt = 0; nt < 8; ++nt) {
      const unsigned short* wp = Wfcb + (size_t)(wave * 128 + nt * 16 + tn) * 512 + k0 + quad * 8;
      acc[nt] = MFMA16(af, ldbf8(wp), acc[nt]);
    }
  }
  if (quad < 2) {
    #pragma unroll
    for (int nt = 0; nt < 8; ++nt) {
      int col = wave * 128 + nt * 16 + tn;
      #pragma unroll
      for (int i = 0; i < 4; ++i) xb[(quad * 4 + i) * XPITCH + col] = acc[nt][i];
    }
  }
  __syncthreads();

  #pragma unroll
  for (int ri = 0; ri < 2; ++ri) {
    int r = wave * 2 + ri;
    int row = m0 + r;
    float* xr = xb + r * XPITCH;
    const float* qr = resid + (size_t)row * 512;
    float sum = 0.f, sq = 0.f;
    #pragma unroll
    for (int it = 0; it < 2; ++it) {
      int i4 = lane + it * 64;  // 0..127
      fx4 x = *reinterpret_cast<fx4*>(xr + i4 * 4);
      fx4 bb = *reinterpret_cast<const fx4*>(bfc + i4 * 4);
      fx4 rr = *reinterpret_cast<const fx4*>(qr + i4 * 4);
      x = x + bb + rr;
      *reinterpret_cast<fx4*>(xr + i4 * 4) = x;
      sum += x[0] + x[1] + x[2] + x[3];
      sq  += x[0]*x[0] + x[1]*x[1] + x[2]*x[2] + x[3]*x[3];
    }
    #pragma unroll
    for (int off = 32; off; off >>= 1) {
      sum += __shfl_xor(sum, off);
      sq  += __shfl_xor(sq, off);
    }
    float mu = sum * (1.f / 512.f);
    float var = sq * (1.f / 512.f) - mu * mu;
    float rstd = rsqrtf(var + 1e-5f);
    #pragma unroll
    for (int it = 0; it < 2; ++it) {
      int i4 = lane + it * 64;
      fx4 x = *reinterpret_cast<fx4*>(xr + i4 * 4);
      fx4 gg = *reinterpret_cast<const fx4*>(lng + i4 * 4);
      fx4 be = *reinterpret_cast<const fx4*>(lnb + i4 * 4);
      fx4 y = (x - mu) * rstd * gg + be;
      *reinterpret_cast<fx4*>(out + (size_t)row * 512 + i4 * 4) = y;
    }
  }
}

// ---------------- launcher ------------------------------------------------------
extern "C" void kernel_launch(void* const* d_in, const int* in_sizes, int n_in,
                              void* d_out, int out_size, void* d_ws, size_t ws_size,
                              hipStream_t stream) {
  const float* q    = (const float*)d_in[0];
  const float* k    = (const float*)d_in[1];
  const float* v    = (const float*)d_in[2];
  const int*   mask = (const int*)d_in[3];
  const float* gate = (const float*)d_in[4];
  const float* w_qs = (const float*)d_in[5];
  const float* b_qs = (const float*)d_in[6];
  const float* w_ks = (const float*)d_in[7];
  const float* b_ks = (const float*)d_in[8];
  const float* w_vs = (const float*)d_in[9];
  const float* b_vs = (const float*)d_in[10];
  const float* w_fc = (const float*)d_in[11];
  const float* b_fc = (const float*)d_in[12];
  const float* ln_g = (const float*)d_in[13];
  const float* ln_b = (const float*)d_in[14];
  float* out = (float*)d_out;

  char* ws = (char*)d_ws;
  unsigned short* Qb = (unsigned short*)(ws);                    //  4 MB
  unsigned short* Kb = (unsigned short*)(ws + 4194304);          //  4 MB
  unsigned short* Vt = (unsigned short*)(ws + 8388608);          //  4 MB
  unsigned short* Ob = (unsigned short*)(ws + 12582912);         //  4 MB
  unsigned short* Wb = (unsigned short*)(ws + 16777216);         //  2 MB (4 x 512KB)
  unsigned long long* mbits = (unsigned long long*)(ws + 18874368);  // 1 MB

  float* attn = out + 2097152;   // [B,H,L,L] f32 attention output region

  k_prep<<<33792, 256, 0, stream>>>(w_qs, w_ks, w_vs, w_fc, Wb, mask, mbits);
  k_proj<<<dim3(64, 8, 3), 256, 0, stream>>>(q, k, v, Wb, b_qs, b_ks, b_vs, Qb, Kb, Vt);
  k_attn<<<4096, 512, 0, stream>>>(Qb, Kb, Vt, gate, mbits, attn, Ob);
  k_fc_ln<<<512, 256, 0, stream>>>(Ob, Wb + 786432, b_fc, q, ln_g, ln_b, out);
}

// Round 6
// 706.227 us; speedup vs baseline: 1.1300x; 1.1300x over previous
//
#include <hip/hip_runtime.h>
#include <stdint.h>

// Problem constants
// B=2, L=2048, D=512, H=8, DK=DV=64, TEMP=8, LN_EPS=1e-5

typedef float fx4 __attribute__((ext_vector_type(4)));
typedef short bfx8 __attribute__((ext_vector_type(8)));
typedef short sx4 __attribute__((ext_vector_type(4)));

#define MFMA16(a, b, c) __builtin_amdgcn_mfma_f32_16x16x32_bf16((a), (b), (c), 0, 0, 0)

__device__ __forceinline__ unsigned short f2bf(float f) {
  union { float f; uint32_t u; } v; v.f = f;
  uint32_t r = v.u + 0x7FFFu + ((v.u >> 16) & 1u);  // RNE
  return (unsigned short)(r >> 16);
}

__device__ __forceinline__ bfx8 ldbf8(const unsigned short* p) {
  return *reinterpret_cast<const bfx8*>(p);
}

__device__ __forceinline__ bfx8 cvt8(const float* p) {
  fx4 a = *reinterpret_cast<const fx4*>(p);
  fx4 b = *reinterpret_cast<const fx4*>(p + 4);
  bfx8 r;
  r[0] = (short)f2bf(a[0]); r[1] = (short)f2bf(a[1]);
  r[2] = (short)f2bf(a[2]); r[3] = (short)f2bf(a[3]);
  r[4] = (short)f2bf(b[0]); r[5] = (short)f2bf(b[1]);
  r[6] = (short)f2bf(b[2]); r[7] = (short)f2bf(b[3]);
  return r;
}

// LDS-only barrier: waits lgkmcnt(0) but leaves global stores (vmcnt) in flight
// so the attn f32 write stream retires under the following MFMA phase.
__device__ __forceinline__ void bar_lgkm() {
  asm volatile("s_waitcnt lgkmcnt(0)\n\ts_barrier" ::: "memory");
  __builtin_amdgcn_sched_barrier(0);
}

// ---------------- kernel 0: weight bf16 convert + mask bitpack (fused) ----------
__global__ __launch_bounds__(256) void k_prep(const float* __restrict__ s0,
                                              const float* __restrict__ s1,
                                              const float* __restrict__ s2,
                                              const float* __restrict__ s3,
                                              unsigned short* __restrict__ dst,
                                              const int* __restrict__ mask,
                                              unsigned long long* __restrict__ mbits) {
  int bid = blockIdx.x;
  if (bid < 1024) {
    int y = bid >> 8;
    const float* s = (y == 0) ? s0 : (y == 1) ? s1 : (y == 2) ? s2 : s3;
    int i = ((bid & 255) * 256 + threadIdx.x) * 4;
    fx4 v = *reinterpret_cast<const fx4*>(s + i);
    sx4 o;
    o[0] = (short)f2bf(v[0]); o[1] = (short)f2bf(v[1]);
    o[2] = (short)f2bf(v[2]); o[3] = (short)f2bf(v[3]);
    *reinterpret_cast<sx4*>(dst + y * 262144 + i) = o;
  } else {
    int i = (bid - 1024) * 256 + threadIdx.x;  // total 8388608
    unsigned long long b = __ballot(mask[i] != 0);
    if ((threadIdx.x & 63) == 0) mbits[i >> 6] = b;
  }
}

// ---------------- kernel 1: projection GEMMs, all 3 in one launch (blockIdx.z) --
// z=0: Qb [B,H,L,64] ; z=1: Kb same ; z=2: Vt [B,H,64,L] (transposed)
__global__ __launch_bounds__(256) void k_proj(const float* __restrict__ Xq,
                                              const float* __restrict__ Xk,
                                              const float* __restrict__ Xv,
                                              const unsigned short* __restrict__ Wb,
                                              const float* __restrict__ bq,
                                              const float* __restrict__ bk,
                                              const float* __restrict__ bv,
                                              unsigned short* __restrict__ Qb,
                                              unsigned short* __restrict__ Kb,
                                              unsigned short* __restrict__ Vt) {
  int z = blockIdx.z;
  const float* X = (z == 0) ? Xq : (z == 1) ? Xk : Xv;
  const unsigned short* W = Wb + (size_t)z * 262144;
  const float* bias = (z == 0) ? bq : (z == 1) ? bk : bv;
  unsigned short* dst = (z == 0) ? Qb : (z == 1) ? Kb : Vt;

  int wave = threadIdx.x >> 6, lane = threadIdx.x & 63;
  int quad = lane >> 4, tn = lane & 15;
  int m0 = blockIdx.x * 64 + wave * 16;   // 64 blocks.x -> 4096 rows
  int n0 = blockIdx.y * 64;               // 8 blocks.y  -> 512 cols
  fx4 acc[4];
  #pragma unroll
  for (int i = 0; i < 4; ++i) acc[i] = (fx4){0.f, 0.f, 0.f, 0.f};

  const float* xrow = X + (size_t)(m0 + tn) * 512;
  for (int k0 = 0; k0 < 512; k0 += 32) {
    bfx8 af = cvt8(xrow + k0 + quad * 8);
    #pragma unroll
    for (int nt = 0; nt < 4; ++nt) {
      const unsigned short* wp = W + (size_t)(n0 + nt * 16 + tn) * 512 + k0 + quad * 8;
      acc[nt] = MFMA16(af, ldbf8(wp), acc[nt]);
    }
  }

  #pragma unroll
  for (int nt = 0; nt < 4; ++nt) {
    int n = n0 + nt * 16 + tn;
    int h = n >> 6, dd = n & 63;
    float bvv = bias[n];
    if (z == 2) {
      int r0 = m0 + quad * 4;          // 4 consecutive rows, same batch
      int b = r0 >> 11, l = r0 & 2047;
      sx4 o;
      #pragma unroll
      for (int i = 0; i < 4; ++i) o[i] = (short)f2bf(acc[nt][i] + bvv);
      unsigned short* vp = dst + (size_t)((b * 8 + h) * 64 + dd) * 2048 + l;
      *reinterpret_cast<sx4*>(vp) = o;
    } else {
      #pragma unroll
      for (int i = 0; i < 4; ++i) {
        int r = m0 + quad * 4 + i;
        int b = r >> 11, l = r & 2047;
        dst[(size_t)((b * 8 + h) * 2048 + l) * 64 + dd] = f2bf(acc[nt][i] + bvv);
      }
    }
  }
}

// ---------------- kernel 2: single-pass attention, 16 q-rows, 8 waves ----------
// Phase A: QK^T -> LDS raw S; gate prefetched per iteration (stream under MFMA).
// Phase B: per wave 2 rows: gate*mask, softmax, write normalized attn f32 +
//          normalized bf16 P into the row's LDS front.
// Phase D: split-K PV across ALL 8 waves; lgkm-only barriers so the attn write
//          stream (vmcnt) retires under PV MFMA instead of draining at a barrier.
#define SPITCH 2052
__global__ __launch_bounds__(512) void k_attn(const unsigned short* __restrict__ Qb,
                                              const unsigned short* __restrict__ Kb,
                                              const unsigned short* __restrict__ Vt,
                                              const float* __restrict__ gate,
                                              const unsigned long long* __restrict__ mbits,
                                              float* __restrict__ attn_out,
                                              unsigned short* __restrict__ Ob) {
  __shared__ float S[16 * SPITCH];   // 131.3 KB score strip (front reused for bf16 P)
  __shared__ float Opart[4 * 16 * 16];  // 4 KB split-K partials

  int wave = threadIdx.x >> 6, lane = threadIdx.x & 63;
  int quad = lane >> 4, tn = lane & 15;

  int lin = blockIdx.x;            // 0..2047
  int xcd = lin & 7;
  int ix  = lin >> 3;              // 0..255
  int bh  = xcd * 2 + (ix >> 7);   // each XCD owns 2 (b,h): K/V stay L2-resident
  int qt  = ix & 127;
  int b = bh >> 3, h = bh & 7;
  int q0 = qt * 16;

  // ---- phase A: raw scores (QK^T)/8 -> LDS, gate prefetch interleaved --------
  const unsigned short* Qbase = Qb + ((size_t)bh * 2048 + q0) * 64;
  bfx8 aq0 = ldbf8(Qbase + tn * 64 + quad * 8);
  bfx8 aq1 = ldbf8(Qbase + tn * 64 + 32 + quad * 8);
  const unsigned short* Kbase = Kb + (size_t)bh * 2048 * 64;
  const float* grow0 = gate + ((size_t)bh * 2048 + q0 + wave * 2) * 2048;

  fx4 gv[16];   // 2 rows x 8 fx4 chunks, fully unrolled -> stays in VGPRs
  #pragma unroll
  for (int i2 = 0; i2 < 16; ++i2) {
    int kt = wave + i2 * 8;        // 16 key-tiles per wave, 8 waves cover 128
    int key0 = kt * 16;
    gv[i2] = *reinterpret_cast<const fx4*>(
        grow0 + (size_t)(i2 >> 3) * 2048 + (size_t)(lane + (i2 & 7) * 64) * 4);
    const unsigned short* kp = Kbase + (size_t)(key0 + tn) * 64 + quad * 8;
    bfx8 b0 = ldbf8(kp);
    bfx8 b1 = ldbf8(kp + 32);
    fx4 d = (fx4){0.f, 0.f, 0.f, 0.f};
    d = MFMA16(aq0, b0, d);
    d = MFMA16(aq1, b1, d);
    #pragma unroll
    for (int i = 0; i < 4; ++i)
      S[(quad * 4 + i) * SPITCH + key0 + tn] = d[i] * 0.125f;
  }
  bar_lgkm();

  // ---- phase B: wave w owns rows 2w, 2w+1 ------------------------------------
  #pragma unroll
  for (int rr = 0; rr < 2; ++rr) {
    int r = wave * 2 + rr;
    float* srow = S + r * SPITCH;
    const unsigned long long* mrow = mbits + (size_t)(b * 2048 + q0 + r) * 32;
    unsigned long long mv[8];
    #pragma unroll
    for (int it = 0; it < 8; ++it) mv[it] = mrow[(lane + it * 64) >> 4];
    fx4 sv[8];
    float lmax = -3.0e38f;
    #pragma unroll
    for (int it = 0; it < 8; ++it) {
      int k4 = lane + it * 64;     // fx4 index 0..511
      fx4 s = *reinterpret_cast<fx4*>(srow + k4 * 4);
      fx4 g = gv[rr * 8 + it];
      int sh = (k4 & 15) * 4;
      #pragma unroll
      for (int i = 0; i < 4; ++i) {
        float vv = s[i] * g[i];
        if ((mv[it] >> (sh + i)) & 1ull) vv = -3.0e38f;
        s[i] = vv;
        lmax = fmaxf(lmax, vv);
      }
      sv[it] = s;
    }
    #pragma unroll
    for (int off = 32; off; off >>= 1) lmax = fmaxf(lmax, __shfl_xor(lmax, off));
    float lsum = 0.f;
    #pragma unroll
    for (int it = 0; it < 8; ++it) {
      fx4 s = sv[it];
      #pragma unroll
      for (int i = 0; i < 4; ++i) {
        float p = __expf(s[i] - lmax);
        s[i] = p;
        lsum += p;
      }
      sv[it] = s;
    }
    #pragma unroll
    for (int off = 32; off; off >>= 1) lsum += __shfl_xor(lsum, off);
    float inv = 1.0f / lsum;
    float* orow = attn_out + ((size_t)bh * 2048 + q0 + r) * 2048;
    unsigned short* pb = reinterpret_cast<unsigned short*>(srow);  // row front, bf16 P
    #pragma unroll
    for (int it = 0; it < 8; ++it) {
      int k4 = lane + it * 64;
      fx4 p = sv[it] * inv;
      *reinterpret_cast<fx4*>(orow + k4 * 4) = p;   // normalized attn (coalesced)
      sx4 pk;
      #pragma unroll
      for (int i = 0; i < 4; ++i) pk[i] = (short)f2bf(p[i]);
      *reinterpret_cast<sx4*>(pb + k4 * 4) = pk;    // normalized bf16 P for PV
    }
  }
  bar_lgkm();   // LDS-only: attn f32 stores keep retiring under phase D's MFMA

  // ---- phase D: split-K PV, all 8 waves. wave w: dv [16(w&3),+16), half w>>2 --
  {
    int kw = wave & 3;
    int kh = wave >> 2;            // key half: 0 -> tiles 0..31, 1 -> 32..63
    fx4 acc = (fx4){0.f, 0.f, 0.f, 0.f};
    const unsigned short* vbase = Vt + ((size_t)bh * 64 + kw * 16 + tn) * 2048;
    const unsigned short* prow = reinterpret_cast<const unsigned short*>(S + tn * SPITCH);
    #pragma unroll 8
    for (int kt = 0; kt < 32; ++kt) {
      int k2 = kh * 32 + kt;
      bfx8 af = ldbf8(prow + k2 * 32 + quad * 8);
      bfx8 bv = ldbf8(vbase + k2 * 32 + quad * 8);
      acc = MFMA16(af, bv, acc);
    }
    if (kh == 1) {
      #pragma unroll
      for (int i = 0; i < 4; ++i)
        Opart[kw * 256 + (quad * 4 + i) * 16 + tn] = acc[i];
    }
    bar_lgkm();
    if (kh == 0) {
      #pragma unroll
      for (int i = 0; i < 4; ++i) {
        float o = acc[i] + Opart[kw * 256 + (quad * 4 + i) * 16 + tn];
        int qg = q0 + quad * 4 + i;
        Ob[(size_t)(b * 2048 + qg) * 512 + h * 64 + kw * 16 + tn] = f2bf(o);
      }
    }
  }
}

// ---------------- kernel 3: FC + bias + residual + LayerNorm --------------------
#define XPITCH 516
__global__ __launch_bounds__(256) void k_fc_ln(const unsigned short* __restrict__ Ob,
                                               const unsigned short* __restrict__ Wfcb,
                                               const float* __restrict__ bfc,
                                               const float* __restrict__ resid,
                                               const float* __restrict__ lng,
                                               const float* __restrict__ lnb,
                                               float* __restrict__ out) {
  __shared__ float xb[16 * XPITCH];
  int wave = threadIdx.x >> 6, lane = threadIdx.x & 63;
  int quad = lane >> 4, tn = lane & 15;
  int m0 = blockIdx.x * 16;   // 256 blocks -> 4096 rows

  fx4 acc[8];
  #pragma unroll
  for (int i = 0; i < 8; ++i) acc[i] = (fx4){0.f, 0.f, 0.f, 0.f};

  const unsigned short* arow = Ob + (size_t)(m0 + tn) * 512;
  for (int k0 = 0; k0 < 512; k0 += 32) {
    bfx8 af = ldbf8(arow + k0 + quad * 8);
    #pragma unroll
    for (int nt = 0; nt < 8; ++nt) {
      const unsigned short* wp = Wfcb + (size_t)(wave * 128 + nt * 16 + tn) * 512 + k0 + quad * 8;
      acc[nt] = MFMA16(af, ldbf8(wp), acc[nt]);
    }
  }
  #pragma unroll
  for (int nt = 0; nt < 8; ++nt) {
    int col = wave * 128 + nt * 16 + tn;
    #pragma unroll
    for (int i = 0; i < 4; ++i) xb[(quad * 4 + i) * XPITCH + col] = acc[nt][i];
  }
  __syncthreads();

  #pragma unroll
  for (int ri = 0; ri < 4; ++ri) {
    int r = wave * 4 + ri;
    int row = m0 + r;
    float* xr = xb + r * XPITCH;
    const float* qr = resid + (size_t)row * 512;
    float sum = 0.f, sq = 0.f;
    #pragma unroll
    for (int it = 0; it < 2; ++it) {
      int i4 = lane + it * 64;  // 0..127
      fx4 x = *reinterpret_cast<fx4*>(xr + i4 * 4);
      fx4 bb = *reinterpret_cast<const fx4*>(bfc + i4 * 4);
      fx4 rr = *reinterpret_cast<const fx4*>(qr + i4 * 4);
      x = x + bb + rr;
      *reinterpret_cast<fx4*>(xr + i4 * 4) = x;
      sum += x[0] + x[1] + x[2] + x[3];
      sq  += x[0]*x[0] + x[1]*x[1] + x[2]*x[2] + x[3]*x[3];
    }
    #pragma unroll
    for (int off = 32; off; off >>= 1) {
      sum += __shfl_xor(sum, off);
      sq  += __shfl_xor(sq, off);
    }
    float mu = sum * (1.f / 512.f);
    float var = sq * (1.f / 512.f) - mu * mu;
    float rstd = rsqrtf(var + 1e-5f);
    #pragma unroll
    for (int it = 0; it < 2; ++it) {
      int i4 = lane + it * 64;
      fx4 x = *reinterpret_cast<fx4*>(xr + i4 * 4);
      fx4 gg = *reinterpret_cast<const fx4*>(lng + i4 * 4);
      fx4 be = *reinterpret_cast<const fx4*>(lnb + i4 * 4);
      fx4 y = (x - mu) * rstd * gg + be;
      *reinterpret_cast<fx4*>(out + (size_t)row * 512 + i4 * 4) = y;
    }
  }
}

// ---------------- launcher ------------------------------------------------------
extern "C" void kernel_launch(void* const* d_in, const int* in_sizes, int n_in,
                              void* d_out, int out_size, void* d_ws, size_t ws_size,
                              hipStream_t stream) {
  const float* q    = (const float*)d_in[0];
  const float* k    = (const float*)d_in[1];
  const float* v    = (const float*)d_in[2];
  const int*   mask = (const int*)d_in[3];
  const float* gate = (const float*)d_in[4];
  const float* w_qs = (const float*)d_in[5];
  const float* b_qs = (const float*)d_in[6];
  const float* w_ks = (const float*)d_in[7];
  const float* b_ks = (const float*)d_in[8];
  const float* w_vs = (const float*)d_in[9];
  const float* b_vs = (const float*)d_in[10];
  const float* w_fc = (const float*)d_in[11];
  const float* b_fc = (const float*)d_in[12];
  const float* ln_g = (const float*)d_in[13];
  const float* ln_b = (const float*)d_in[14];
  float* out = (float*)d_out;

  char* ws = (char*)d_ws;
  unsigned short* Qb = (unsigned short*)(ws);                    //  4 MB
  unsigned short* Kb = (unsigned short*)(ws + 4194304);          //  4 MB
  unsigned short* Vt = (unsigned short*)(ws + 8388608);          //  4 MB
  unsigned short* Ob = (unsigned short*)(ws + 12582912);         //  4 MB
  unsigned short* Wb = (unsigned short*)(ws + 16777216);         //  2 MB (4 x 512KB)
  unsigned long long* mbits = (unsigned long long*)(ws + 18874368);  // 1 MB

  float* attn = out + 2097152;   // [B,H,L,L] f32 attention output region

  k_prep<<<33792, 256, 0, stream>>>(w_qs, w_ks, w_vs, w_fc, Wb, mask, mbits);
  k_proj<<<dim3(64, 8, 3), 256, 0, stream>>>(q, k, v, Wb, b_qs, b_ks, b_vs, Qb, Kb, Vt);
  k_attn<<<2048, 512, 0, stream>>>(Qb, Kb, Vt, gate, mbits, attn, Ob);
  k_fc_ln<<<256, 256, 0, stream>>>(Ob, Wb + 786432, b_fc, q, ln_g, ln_b, out);
}